// Round 14
// baseline (349.406 us; speedup 1.0000x reference)
//
#include <hip/hip_runtime.h>
#include <hip/hip_bf16.h>

#define N_NODES 50000
#define N_EDGES 800000
#define NB 196   // ceil(N_NODES/256)
#define NBK 512  // bucket-pass blocks (2/CU)
#define EPB 1563 // edges per bucket-pass block (512*1563 >= 800000)
#define GBLK 391 // gemm blocks = ceil(N_NODES/128); also # of pool partials
#define NWAVES 8192  // streaming aggregation waves

typedef __attribute__((ext_vector_type(8))) short short8;
typedef __attribute__((ext_vector_type(4))) float f32x4;
typedef __attribute__((ext_vector_type(2))) float f32x2;

// int8 message quantization.
// Layer 2: h1 rows L2-normalized => |msg2| <= ||w_col||+|b| ~= 1.15 < 2 (hard).
// Layer 1: |msg1| <= max||x||*max||wp1_col||+|b| ~= 11.2*1.05+0.2 < 12.75 (hard).
#define QSCALE2 (2.f / 255.f)
#define QINV2   127.5f
#define QSCALE1 (12.75f / 255.f)   // = 0.05
#define QINV1   20.f

__device__ __forceinline__ float us2f(unsigned short u) {
    return __uint_as_float(((unsigned int)u) << 16);
}
__device__ __forceinline__ unsigned short f2bu(float f) {
    unsigned int u = __float_as_uint(f);
    unsigned int r = (u + 0x7fffu + ((u >> 16) & 1u)) >> 16;  // RNE
    return (unsigned short)r;
}
__device__ __forceinline__ float exp2_hw(float x) {
    float r;
    __asm__("v_exp_f32 %0, %1" : "=v"(r) : "v"(x));
    return r;
}
// async global->LDS, 16B per lane; LDS dest = wave-uniform base + lane*16
__device__ __forceinline__ void async16(const void* g, void* l) {
    __builtin_amdgcn_global_load_lds(
        (const __attribute__((address_space(1))) unsigned int*)g,
        (__attribute__((address_space(3))) unsigned int*)l, 16, 0, 0);
}
#define LOG2E 1.44269504088896f

// ---------------- CSR build ----------------
// k_hist fused into k_bhist: one pass over dst does both the per-node global
// atomicAdd (commutative -> deterministic) and the 196-bucket LDS histogram.
__global__ __launch_bounds__(256) void k_bhist(const int* __restrict__ dst,
                                               int* __restrict__ counts,
                                               int* __restrict__ bcnt) {
    __shared__ int h[196];
    int t = threadIdx.x, b = blockIdx.x;
    if (t < 196) h[t] = 0;
    __syncthreads();
    int e0 = b * EPB, e1 = e0 + EPB < N_EDGES ? e0 + EPB : N_EDGES;
    for (int e = e0 + t; e < e1; e += 256) {
        int d = dst[e];
        atomicAdd(&h[d >> 8], 1);   // LDS bucket histogram
        atomicAdd(&counts[d], 1);   // global per-node count (avg 16/counter)
    }
    __syncthreads();
    if (t < 196) bcnt[b * 196 + t] = h[t];
}

__global__ __launch_bounds__(256) void k_scan1(const int* __restrict__ counts,
                                               int* __restrict__ row_ptr,
                                               int* __restrict__ partial) {
    __shared__ int sd[256];
    int t = threadIdx.x, i = blockIdx.x * 256 + t;
    int v = (i < N_NODES) ? counts[i] : 0;
    sd[t] = v;
    __syncthreads();
    for (int off = 1; off < 256; off <<= 1) {
        int o = (t >= off) ? sd[t - off] : 0;
        __syncthreads();
        sd[t] += o;
        __syncthreads();
    }
    if (i < N_NODES) row_ptr[i] = sd[t] - v;
    if (t == 255) partial[blockIdx.x] = sd[255];
}

// scan3b: each block computes its own base (sum of partial[0..b-1]) then globalizes.
__global__ __launch_bounds__(256) void k_scan3b(int* __restrict__ row_ptr,
                                                const int* __restrict__ partial) {
    __shared__ int sd[256];
    int t = threadIdx.x;
    sd[t] = (t < blockIdx.x) ? partial[t] : 0;  // blockIdx < NB=196 < 256
    __syncthreads();
    for (int off = 128; off > 0; off >>= 1) {
        if (t < off) sd[t] += sd[t + off];
        __syncthreads();
    }
    int base = sd[0];
    int i = blockIdx.x * 256 + t;
    if (i < N_NODES) row_ptr[i] += base;
    if (blockIdx.x == 0 && t == 0) row_ptr[N_NODES] = N_EDGES;
}

// block q (196 blocks, 512 threads): exclusive scan of bcnt[b][q] over b.
__global__ __launch_bounds__(512) void k_bscan(const int* __restrict__ bcnt,
                                               const int* __restrict__ row_ptr,
                                               int* __restrict__ boff) {
    __shared__ int sd[512];
    int q = blockIdx.x, t = threadIdx.x;
    int v = bcnt[t * 196 + q];  // t < 512 = NBK
    sd[t] = v;
    __syncthreads();
    for (int off = 1; off < 512; off <<= 1) {
        int o = (t >= off) ? sd[t - off] : 0;
        __syncthreads();
        sd[t] += o;
        __syncthreads();
    }
    boff[t * 196 + q] = row_ptr[q * 256] + sd[t] - v;
}

__global__ __launch_bounds__(256) void k_bucket2(const int* __restrict__ src,
                                                 const int* __restrict__ dst,
                                                 const int* __restrict__ boff,
                                                 int* __restrict__ tmp) {
    __shared__ int lcur[196];
    int t = threadIdx.x, b = blockIdx.x;
    if (t < 196) lcur[t] = boff[b * 196 + t];
    __syncthreads();
    int e0 = b * EPB, e1 = e0 + EPB < N_EDGES ? e0 + EPB : N_EDGES;
    for (int e = e0 + t; e < e1; e += 256) {
        int d = dst[e];
        int pos = atomicAdd(&lcur[d >> 8], 1);  // LDS atomic: intra-block only
        tmp[pos] = src[e] | ((d & 255) << 16);  // src<50000<2^16
    }
}

__global__ __launch_bounds__(256) void k_scatter2(const int* __restrict__ row_ptr,
                                                  const int* __restrict__ tmp,
                                                  int* __restrict__ src_sorted) {
    __shared__ int lcur[256];
    int b = blockIdx.x, t = threadIdx.x;
    int n0 = b * 256;
    int nhi = n0 + 256 < N_NODES ? n0 + 256 : N_NODES;
    if (n0 + t < nhi) lcur[t] = row_ptr[n0 + t];
    __syncthreads();
    int ebeg = row_ptr[n0], eend = row_ptr[nhi];
    for (int i = ebeg + t; i < eend; i += 256) {
        int w = tmp[i];
        int pos = atomicAdd(&lcur[(w >> 16) & 255], 1);  // LDS atomic
        src_sorted[pos] = w & 0xFFFF;
    }
}

// ---------------- equal-edge wave partition ----------------
__global__ __launch_bounds__(256) void k_split(const int* __restrict__ row_ptr,
                                               int* __restrict__ split) {
    int w = blockIdx.x * 256 + threadIdx.x;
    if (w > NWAVES) return;
    if (w == NWAVES) { split[w] = N_NODES; return; }
    int target = (int)((long long)w * N_EDGES / NWAVES);
    int lo = 0, hi = N_NODES;
    while (lo < hi) {
        int mid = (lo + hi) >> 1;
        if (row_ptr[mid] < target) lo = mid + 1; else hi = mid;
    }
    split[w] = lo;
}

// ---------------- fused cast/transpose prep (float4-vectorized) ----------------
#define XCAST_N (N_NODES * 64)
#define PREP_TOT (XCAST_N + 167936)
__global__ __launch_bounds__(256) void k_prep(const float* __restrict__ x,
                                              const float* __restrict__ wp1,
                                              const float* __restrict__ wl1,
                                              const float* __restrict__ wr1,
                                              const float* __restrict__ wp2,
                                              const float* __restrict__ wl2,
                                              const float* __restrict__ wr2,
                                              unsigned short* __restrict__ cat1,
                                              unsigned short* __restrict__ B0T,
                                              unsigned short* __restrict__ B1T,
                                              unsigned short* __restrict__ BP2T,
                                              unsigned short* __restrict__ B2T) {
    int idx = (blockIdx.x * 256 + threadIdx.x) * 4;
    if (idx < XCAST_N) {
        int i = idx >> 6, j = idx & 63;
        float4 v = *(const float4*)&x[idx];
        ushort4 o = { f2bu(v.x), f2bu(v.y), f2bu(v.z), f2bu(v.w) };
        *(ushort4*)&cat1[i * 128 + 64 + j] = o;
        return;
    }
    int w = idx - XCAST_N;
    if (w < 4096)  { float4 v = *(const float4*)&wp1[w]; int k = w >> 6, n = w & 63;
                     B0T[n*64+k]=f2bu(v.x); B0T[(n+1)*64+k]=f2bu(v.y);
                     B0T[(n+2)*64+k]=f2bu(v.z); B0T[(n+3)*64+k]=f2bu(v.w); return; }
    w -= 4096;
    if (w < 16384) { float4 v = *(const float4*)&wl1[w]; int k = w >> 8, n = w & 255;
                     B1T[n*128+k]=f2bu(v.x); B1T[(n+1)*128+k]=f2bu(v.y);
                     B1T[(n+2)*128+k]=f2bu(v.z); B1T[(n+3)*128+k]=f2bu(v.w); return; }
    w -= 16384;
    if (w < 16384) { float4 v = *(const float4*)&wr1[w]; int k = w >> 8, n = w & 255;
                     B1T[n*128+64+k]=f2bu(v.x); B1T[(n+1)*128+64+k]=f2bu(v.y);
                     B1T[(n+2)*128+64+k]=f2bu(v.z); B1T[(n+3)*128+64+k]=f2bu(v.w); return; }
    w -= 16384;
    if (w < 65536) { float4 v = *(const float4*)&wp2[w]; int k = w >> 8, n = w & 255;
                     BP2T[n*256+k]=f2bu(v.x); BP2T[(n+1)*256+k]=f2bu(v.y);
                     BP2T[(n+2)*256+k]=f2bu(v.z); BP2T[(n+3)*256+k]=f2bu(v.w); return; }
    w -= 65536;
    if (w < 32768) { float4 v = *(const float4*)&wl2[w]; int k = w >> 7, n = w & 127;
                     B2T[n*512+k]=f2bu(v.x); B2T[(n+1)*512+k]=f2bu(v.y);
                     B2T[(n+2)*512+k]=f2bu(v.z); B2T[(n+3)*512+k]=f2bu(v.w); return; }
    w -= 32768;
    if (w < 32768) { float4 v = *(const float4*)&wr2[w]; int k = w >> 7, n = w & 127;
                     B2T[n*512+256+k]=f2bu(v.x); B2T[(n+1)*512+256+k]=f2bu(v.y);
                     B2T[(n+2)*512+256+k]=f2bu(v.z); B2T[(n+3)*512+256+k]=f2bu(v.w); return; }
}

// ---------------- MFMA bf16 GEMM, 128-row tile, async staging, fused epilogue ----
// PIPE=1: 2-phase pipelined staging (double-buffered LDS).
// EP2 now fully fuses the MemPool: softmax S stays in LDS (sS), the per-block
// partial sum S^T h2 [4][128] is computed from the rp staging buffer, and only
// a 512-float partial per block is written (h2/Sm global round-trip deleted).
template<int K, int C, int LDA, int LDOUT, int OUT_OFF, int EP, int WPB, int MH, int PIPE>
__global__ __launch_bounds__(256, WPB) void k_gemm(const unsigned short* __restrict__ A,
                                                   const unsigned short* __restrict__ BT,
                                                   const float* __restrict__ bias,
                                                   void* __restrict__ outv,
                                                   const float* __restrict__ kmem,
                                                   const float* __restrict__ wconv,
                                                   float* __restrict__ Sm,
                                                   float qinv) {
    constexpr int NT = C / 16;
    constexpr int SAE = 64 * MH * 64;  // elems, stride 64 (linear for gload_lds)
    constexpr int SBE = C * 64;
    constexpr int BUFE = SAE + SBE;
    constexpr int STAGE_B = BUFE * 2 * (PIPE ? 2 : 1);
    constexpr int RPLD = (EP == 2) ? (C + 4) : ((EP == 3) ? (C + 16) : (C + 8));
    constexpr int RP_B = 64 * RPLD * (EP == 2 ? 4 : (EP == 3 ? 1 : 2));
    constexpr int SMEM_B = STAGE_B > RP_B ? STAGE_B : RP_B;
    constexpr int POOL_B = (EP == 2) ? (2048 * 4 + 64 + 16 + 1024) : 16;
    __shared__ __align__(16) char smem[SMEM_B + POOL_B];
    unsigned short* sA = (unsigned short*)smem;
    float* kls  = (float*)(smem + SMEM_B);  // EP2 only: 2048 floats
    float* kk2s = kls + 2048;               // 16
    float* wcs  = kk2s + 16;                // 4
    float* sS   = wcs + 4;                  // EP2 only: 64 rows x 4 clusters

    int t = threadIdx.x;
    int wid = t >> 6, lane = t & 63;
    int lrow = lane & 15, quad = lane >> 4;
    int m0 = blockIdx.x * (64 * MH);

    if (EP == 2) {  // stage mempool keys once per block
        for (int i = t; i < 2048; i += 256) kls[i] = kmem[i];
        if (t < 4) wcs[t] = wconv[t];
        __syncthreads();
        if (t < 16) {
            float s = 0.f;
            for (int f = 0; f < 128; ++f) { float v = kls[t * 128 + f]; s += v * v; }
            kk2s[t] = s;
        }
    }

    f32x4 acc[MH][NT];
#pragma unroll
    for (int h = 0; h < MH; ++h)
#pragma unroll
        for (int nt = 0; nt < NT; ++nt)
#pragma unroll
            for (int r = 0; r < 4; ++r) acc[h][nt][r] = 0.f;

    auto stage = [&](int step, int buf) {
        unsigned short* sAb = sA + buf * BUFE;
        unsigned short* sBb = sAb + SAE;
        int k0 = step * 64;
        for (int i = t; i < 64 * MH * 8; i += 256) {
            int r = i >> 3, seg = i & 7;
            size_t m = (size_t)(m0 + r);
            async16(&A[m * LDA + k0 + ((seg ^ (r & 7)) << 3)],
                    (char*)sAb + (size_t)(i - lane) * 16);
        }
        for (int i = t; i < C * 8; i += 256) {
            int n = i >> 3, seg = i & 7;
            async16(&BT[(size_t)n * K + k0 + ((seg ^ (n & 7)) << 3)],
                    (char*)sBb + (size_t)(i - lane) * 16);
        }
    };
    auto compute = [&](int buf) {
        unsigned short* sAb = sA + buf * BUFE;
        unsigned short* sBb = sAb + SAE;
#pragma unroll
        for (int kk = 0; kk < 2; ++kk) {
            int sw = lrow & 7;
            short8 av[MH];
#pragma unroll
            for (int h = 0; h < MH; ++h)
                av[h] = *(const short8*)&sAb[(h * 64 + wid * 16 + lrow) * 64 +
                                             (((kk * 4 + quad) ^ sw) << 3)];
#pragma unroll
            for (int nt = 0; nt < NT; ++nt) {
                short8 bfg = *(const short8*)&sBb[(nt * 16 + lrow) * 64 +
                                                  (((kk * 4 + quad) ^ sw) << 3)];
#pragma unroll
                for (int h = 0; h < MH; ++h)
                    acc[h][nt] = __builtin_amdgcn_mfma_f32_16x16x32_bf16(av[h], bfg, acc[h][nt], 0, 0, 0);
            }
        }
    };

    constexpr int NSTEP = K / 64;
    if (PIPE) {
        stage(0, 0);
        __syncthreads();  // drains stage(0)
        for (int step = 0; step < NSTEP; ++step) {
            int cur = step & 1;
            if (step + 1 < NSTEP) stage(step + 1, cur ^ 1);  // in flight during compute
            compute(cur);
            __syncthreads();  // drains stage(step+1) after it overlapped compute
        }
    } else {
        for (int step = 0; step < NSTEP; ++step) {
            __syncthreads();
            stage(step, 0);
            __syncthreads();
            compute(0);
        }
    }

#pragma unroll
    for (int h = 0; h < MH; ++h) {
#pragma unroll
        for (int nt = 0; nt < NT; ++nt) {
            float bv = bias[nt * 16 + lrow];
#pragma unroll
            for (int r = 0; r < 4; ++r) acc[h][nt][r] += bv;
        }
        if (EP == 1 || EP == 2) {
#pragma unroll
            for (int r = 0; r < 4; ++r) {
                float ss = 0.f;
#pragma unroll
                for (int nt = 0; nt < NT; ++nt) ss += acc[h][nt][r] * acc[h][nt][r];
                ss += __shfl_xor(ss, 1);
                ss += __shfl_xor(ss, 2);
                ss += __shfl_xor(ss, 4);
                ss += __shfl_xor(ss, 8);
                float rinv = 1.f / fmaxf(sqrtf(ss), 1e-12f);
#pragma unroll
                for (int nt = 0; nt < NT; ++nt)
                    acc[h][nt][r] = fmaxf(acc[h][nt][r] * rinv, 0.f);
            }
        } else {
#pragma unroll
            for (int nt = 0; nt < NT; ++nt)
#pragma unroll
                for (int r = 0; r < 4; ++r) acc[h][nt][r] = fmaxf(acc[h][nt][r], 0.f);
        }
    }

    float pacc0 = 0.f, pacc1 = 0.f;  // EP2: this thread's 2 pool-partial outputs

    __syncthreads();
#pragma unroll
    for (int h = 0; h < MH; ++h) {
        if (EP == 2) {
            float* rp = (float*)smem;
#pragma unroll
            for (int nt = 0; nt < NT; ++nt)
#pragma unroll
                for (int r = 0; r < 4; ++r)
                    rp[(wid * 16 + quad * 4 + r) * RPLD + nt * 16 + lrow] = acc[h][nt][r];
            __syncthreads();
            // mempool assignment (4 threads/row, shuffle-combine) -> S into sS LDS
            {
                int row = t >> 2, p = t & 3;
                int cbase = p * 32;
                float dots[16];
#pragma unroll
                for (int k = 0; k < 16; ++k) dots[k] = 0.f;
                float x2 = 0.f;
#pragma unroll
                for (int j = 0; j < 8; ++j) {
                    int c4 = (j + p * 2) & 7;
                    float4 xv = *(const float4*)&rp[row * RPLD + cbase + c4 * 4];
                    x2 += xv.x * xv.x + xv.y * xv.y + xv.z * xv.z + xv.w * xv.w;
#pragma unroll
                    for (int k = 0; k < 16; ++k) {
                        float4 kv = *(const float4*)&kls[k * 128 + cbase + c4 * 4];
                        dots[k] += xv.x * kv.x + xv.y * kv.y + xv.z * kv.z + xv.w * kv.w;
                    }
                }
#pragma unroll
                for (int k = 0; k < 16; ++k) {
                    dots[k] += __shfl_xor(dots[k], 1);
                    dots[k] += __shfl_xor(dots[k], 2);
                }
                x2 += __shfl_xor(x2, 1);
                x2 += __shfl_xor(x2, 2);
                if (p == 0) {
                    int m = m0 + h * 64 + row;
                    float4 sv = make_float4(0.f, 0.f, 0.f, 0.f);
                    if (m < N_NODES) {
                        float dist[16];
#pragma unroll
                        for (int k = 0; k < 16; ++k) {
                            float d2 = fmaxf(kk2s[k] + x2 - 2.f * dots[k], 0.f);
                            dist[k] = 1.f / (1.f + d2);
                        }
                        float s0 = 0.f, s1 = 0.f, s2 = 0.f, s3 = 0.f;
#pragma unroll
                        for (int hh = 0; hh < 4; ++hh) {
                            float den = dist[hh * 4] + dist[hh * 4 + 1] +
                                        dist[hh * 4 + 2] + dist[hh * 4 + 3];
                            float inv = wcs[hh] / den;
                            s0 += dist[hh * 4 + 0] * inv;
                            s1 += dist[hh * 4 + 1] * inv;
                            s2 += dist[hh * 4 + 2] * inv;
                            s3 += dist[hh * 4 + 3] * inv;
                        }
                        float mx = fmaxf(fmaxf(s0, s1), fmaxf(s2, s3));
                        float e0 = __expf(s0 - mx), e1 = __expf(s1 - mx);
                        float e2 = __expf(s2 - mx), e3 = __expf(s3 - mx);
                        float inv = 1.f / (e0 + e1 + e2 + e3);
                        sv = make_float4(e0 * inv, e1 * inv, e2 * inv, e3 * inv);
                    }
                    *(float4*)&sS[row * 4] = sv;
                }
            }
            __syncthreads();
            // per-block partial of S^T h2: output o=t -> (k=t>>7, c=t&127),
            // o=t+256 -> (k=2+(t>>7), c). rp reads stride-1 (conflict-free),
            // sS reads broadcast. OOB rows contribute 0 via sS.
            {
                int c = t & 127, kq = t >> 7;
                for (int r = 0; r < 64; ++r) {
                    float xv = rp[r * RPLD + c];
                    pacc0 = fmaf(sS[r * 4 + kq], xv, pacc0);
                    pacc1 = fmaf(sS[r * 4 + 2 + kq], xv, pacc1);
                }
            }
            __syncthreads();
        } else if (EP == 3) {
            unsigned char* rp = (unsigned char*)smem;
#pragma unroll
            for (int nt = 0; nt < NT; ++nt)
#pragma unroll
                for (int r = 0; r < 4; ++r) {
                    float q = fminf(__builtin_rintf(acc[h][nt][r] * qinv), 255.f);
                    rp[(wid * 16 + quad * 4 + r) * RPLD + nt * 16 + lrow] = (unsigned char)(int)q;
                }
            __syncthreads();
            unsigned char* outp = (unsigned char*)outv;
            for (int i = t; i < 64 * C / 16; i += 256) {
                int f = i * 16, r = f / C, c = f % C;
                int m = m0 + h * 64 + r;
                if (m < N_NODES)
                    *(uint4*)&outp[(size_t)m * LDOUT + OUT_OFF + c] = *(const uint4*)&rp[r * RPLD + c];
            }
            __syncthreads();
        } else {
            unsigned short* rp = (unsigned short*)smem;
#pragma unroll
            for (int nt = 0; nt < NT; ++nt)
#pragma unroll
                for (int r = 0; r < 4; ++r)
                    rp[(wid * 16 + quad * 4 + r) * RPLD + nt * 16 + lrow] = f2bu(acc[h][nt][r]);
            __syncthreads();
            unsigned short* outp = (unsigned short*)outv;
            for (int i = t; i < 64 * C / 8; i += 256) {
                int f = i * 8, r = f / C, c = f % C;
                int m = m0 + h * 64 + r;
                if (m < N_NODES)
                    *(uint4*)&outp[(size_t)m * LDOUT + OUT_OFF + c] = *(const uint4*)&rp[r * RPLD + c];
            }
            __syncthreads();
        }
    }
    if (EP == 2) {
        float* partp = (float*)outv;
        partp[(size_t)blockIdx.x * 512 + t] = pacc0;
        partp[(size_t)blockIdx.x * 512 + 256 + t] = pacc1;
    }
    (void)Sm;
}

// ---------------- streaming segmented softmax aggregation (layer 2) ----------------
// Frozen at the round-10 equilibrium form (6 structural variants all >=51us).
__global__ __launch_bounds__(256, 4) void k_aggr256(const unsigned char* __restrict__ xp,
                                                    const float* __restrict__ tvec,
                                                    const int* __restrict__ row_ptr,
                                                    const int* __restrict__ srcs,
                                                    const int* __restrict__ split,
                                                    unsigned short* __restrict__ outp) {
    int t = threadIdx.x & 63;  // 4 channels per thread
    int w = blockIdx.x * 4 + (threadIdx.x >> 6);
    float4 tv4 = *(const float4*)&tvec[t * 4];
    f32x2 tv01 = {tv4.x * (LOG2E * QSCALE2), tv4.y * (LOG2E * QSCALE2)};
    f32x2 tv23 = {tv4.z * (LOG2E * QSCALE2), tv4.w * (LOG2E * QSCALE2)};
    int n    = __builtin_amdgcn_readfirstlane(split[w]);
    int nend = __builtin_amdgcn_readfirstlane(split[w + 1]);
    if (n >= nend) return;
    int e    = __builtin_amdgcn_readfirstlane(row_ptr[n]);
    int eend = __builtin_amdgcn_readfirstlane(row_ptr[nend]);
    int rp_next = __builtin_amdgcn_readfirstlane(row_ptr[n + 1]);
    f32x2 se01 = {0.f, 0.f}, se23 = {0.f, 0.f};
    f32x2 sem01 = {0.f, 0.f}, sem23 = {0.f, 0.f};

#define FINALIZE()                                                             \
    {                                                                          \
        ushort4 o;                                                             \
        o.x = f2bu(QSCALE2 * sem01.x / fmaxf(se01.x, 1e-16f));                 \
        o.y = f2bu(QSCALE2 * sem01.y / fmaxf(se01.y, 1e-16f));                 \
        o.z = f2bu(QSCALE2 * sem23.x / fmaxf(se23.x, 1e-16f));                 \
        o.w = f2bu(QSCALE2 * sem23.y / fmaxf(se23.y, 1e-16f));                 \
        *(ushort4*)&outp[(size_t)n * 512 + t * 4] = o;                         \
        se01 = (f32x2){0.f, 0.f}; se23 = (f32x2){0.f, 0.f};                    \
        sem01 = (f32x2){0.f, 0.f}; sem23 = (f32x2){0.f, 0.f};                  \
        ++n;                                                                   \
        rp_next = (n < nend) ? __builtin_amdgcn_readfirstlane(row_ptr[n + 1])  \
                             : 0x7FFFFFFF;                                     \
    }
#define EDGE_BODY(VV)                                                          \
    {                                                                          \
        f32x2 m01 = {(float)((VV) & 0xFFu), (float)(((VV) >> 8) & 0xFFu)};     \
        f32x2 m23 = {(float)(((VV) >> 16) & 0xFFu), (float)((VV) >> 24)};      \
        f32x2 l01 = m01 * tv01, l23 = m23 * tv23;                              \
        f32x2 w01, w23;                                                        \
        w01.x = exp2_hw(l01.x); w01.y = exp2_hw(l01.y);                        \
        w23.x = exp2_hw(l23.x); w23.y = exp2_hw(l23.y);                        \
        se01 += w01; se23 += w23;                                              \
        sem01 = __builtin_elementwise_fma(w01, m01, sem01);                    \
        sem23 = __builtin_elementwise_fma(w23, m23, sem23);                    \
    }

    while (rp_next <= e) FINALIZE();  // leading empty nodes (write zeros)

    while (e < eend) {
        unsigned int v[16];
        int rem = eend - e;
        int cnt = rem > 16 ? 16 : rem;
        if (cnt == 16) {
#pragma unroll
            for (int j = 0; j < 16; ++j) {
                const unsigned char* p = xp + (size_t)srcs[e + j] * 256;  // uniform base
                v[j] = *(const unsigned int*)&p[t * 4];
            }
        } else {  // single short batch per wave
#pragma unroll
            for (int j = 0; j < 16; ++j) {
                int ee = e + j;
                ee = ee < eend ? ee : eend - 1;
                const unsigned char* p = xp + (size_t)srcs[ee] * 256;
                v[j] = *(const unsigned int*)&p[t * 4];
            }
        }
#pragma unroll
        for (int j = 0; j < 16; ++j) {
            if (j < cnt) {
                EDGE_BODY(v[j])
                while (e + j + 1 == rp_next) FINALIZE();  // also drains empty nodes
            }
        }
        e += cnt;
    }
#undef EDGE_BODY
#undef FINALIZE
}

// C=64 variant (layer 1): same streaming structure, 1 byte/lane/edge.
__global__ __launch_bounds__(256, 4) void k_aggr64(const unsigned char* __restrict__ xp,
                                                   const float* __restrict__ tvec,
                                                   const int* __restrict__ row_ptr,
                                                   const int* __restrict__ srcs,
                                                   const int* __restrict__ split,
                                                   unsigned short* __restrict__ outp) {
    int c = threadIdx.x & 63;  // channel 0..63
    int w = blockIdx.x * 4 + (threadIdx.x >> 6);
    float tv = tvec[c] * (LOG2E * QSCALE1);
    int n    = __builtin_amdgcn_readfirstlane(split[w]);
    int nend = __builtin_amdgcn_readfirstlane(split[w + 1]);
    if (n >= nend) return;
    int e    = __builtin_amdgcn_readfirstlane(row_ptr[n]);
    int eend = __builtin_amdgcn_readfirstlane(row_ptr[nend]);
    int rp_next = __builtin_amdgcn_readfirstlane(row_ptr[n + 1]);
    float se = 0.f, sem = 0.f;

#define FIN1()                                                                 \
    {                                                                          \
        outp[(size_t)n * 128 + c] = f2bu(QSCALE1 * sem / fmaxf(se, 1e-16f));   \
        se = 0.f; sem = 0.f;                                                   \
        ++n;                                                                   \
        rp_next = (n < nend) ? __builtin_amdgcn_readfirstlane(row_ptr[n + 1])  \
                             : 0x7FFFFFFF;                                     \
    }

    while (rp_next <= e) FIN1();

    while (e < eend) {
        unsigned char v[16];
        int rem = eend - e;
        int cnt = rem > 16 ? 16 : rem;
        if (cnt == 16) {
#pragma unroll
            for (int j = 0; j < 16; ++j)
                v[j] = xp[(size_t)srcs[e + j] * 64 + c];
        } else {
#pragma unroll
            for (int j = 0; j < 16; ++j) {
                int ee = e + j;
                ee = ee < eend ? ee : eend - 1;
                v[j] = xp[(size_t)srcs[ee] * 64 + c];
            }
        }
#pragma unroll
        for (int j = 0; j < 16; ++j) {
            if (j < cnt) {
                float msg = (float)v[j];
                float wv = exp2_hw(msg * tv);
                se += wv;
                sem = fmaf(wv, msg, sem);
                while (e + j + 1 == rp_next) FIN1();
            }
        }
        e += cnt;
    }
#undef FIN1
}

// ---------------- MemPool reduce: sum GBLK block-partials ----------------
__global__ __launch_bounds__(256) void k_pool_b(const float* __restrict__ part,
                                                float* __restrict__ pooled) {
    int j = blockIdx.x;  // 0..511
    float s = 0.f;
    for (int b = threadIdx.x; b < GBLK; b += 256) s += part[(size_t)b * 512 + j];
#pragma unroll
    for (int off = 32; off > 0; off >>= 1) s += __shfl_xor(s, off);
    __shared__ float red[4];
    int lane = threadIdx.x & 63, wid = threadIdx.x >> 6;
    if (lane == 0) red[wid] = s;
    __syncthreads();
    if (threadIdx.x == 0) pooled[j] = red[0] + red[1] + red[2] + red[3];
}

__global__ __launch_bounds__(128) void k_final(const float* __restrict__ pooled,
                                               const float* __restrict__ wmem,
                                               const float* __restrict__ bmem,
                                               const float* __restrict__ wfx,
                                               const float* __restrict__ bfx,
                                               const float* __restrict__ gamma,
                                               const float* __restrict__ beta,
                                               float* __restrict__ out) {
    __shared__ float gx[128], g[128];
    int t = threadIdx.x;
    gx[t] = 0.25f * (pooled[t] + pooled[128 + t] + pooled[256 + t] + pooled[384 + t]);
    __syncthreads();
    float acc = bmem[t];
    for (int f = 0; f < 128; ++f) acc = fmaf(gx[f], wmem[f * 128 + t], acc);
    g[t] = acc;
    __syncthreads();
    if (t < 64) {
        float y = bfx[t];
        for (int f = 0; f < 128; ++f) y = fmaf(g[f], wfx[f * 64 + t], y);
        float s = y, s2 = y * y;
#pragma unroll
        for (int off = 32; off > 0; off >>= 1) {
            s += __shfl_xor(s, off);
            s2 += __shfl_xor(s2, off);
        }
        float mu = s * (1.f / 64.f);
        float var = s2 * (1.f / 64.f) - mu * mu;
        float v = (y - mu) / sqrtf(var + 1e-5f) * gamma[t] + beta[t];
        out[t] = fmaxf(v, 0.f);
    }
}

extern "C" void kernel_launch(void* const* d_in, const int* in_sizes, int n_in,
                              void* d_out, int out_size, void* d_ws, size_t ws_size,
                              hipStream_t stream) {
    const float* x        = (const float*)d_in[0];
    const int*   ei       = (const int*)  d_in[1];
    const float* w_proj1  = (const float*)d_in[2];
    const float* b_proj1  = (const float*)d_in[3];
    const float* t1       = (const float*)d_in[4];
    const float* w_l1     = (const float*)d_in[5];
    const float* b_l1     = (const float*)d_in[6];
    const float* w_r1     = (const float*)d_in[7];
    const float* w_proj2  = (const float*)d_in[8];
    const float* b_proj2  = (const float*)d_in[9];
    const float* t2       = (const float*)d_in[10];
    const float* w_l2     = (const float*)d_in[11];
    const float* b_l2     = (const float*)d_in[12];
    const float* w_r2     = (const float*)d_in[13];
    const float* k_mem    = (const float*)d_in[14];
    const float* w_conv   = (const float*)d_in[15];
    const float* w_memlin = (const float*)d_in[16];
    const float* b_memlin = (const float*)d_in[17];
    const float* w_fx     = (const float*)d_in[18];
    const float* b_fx     = (const float*)d_in[19];
    const float* gamma    = (const float*)d_in[20];
    const float* beta     = (const float*)d_in[21];
    const int* src = ei;
    const int* dst = ei + N_EDGES;
    (void)in_sizes; (void)n_in; (void)out_size; (void)ws_size;

    char* W = (char*)d_ws;
    const size_t MB = 1024 * 1024;
    int*   row_ptr    = (int*)(W + 0);
    int*   counts     = (int*)(W + 256 * 1024);
    int*   partial    = (int*)(W + 512 * 1024);
    int*   split      = (int*)(W + 520 * 1024);              // [NWAVES+1] = 32.8 KB
    int*   src_sorted = (int*)(W + 768 * 1024);
    unsigned short* cat1 = (unsigned short*)(W + 4 * MB);    // [M][128]: 0-63 aggr1, 64-127 x
    unsigned char*  xp1  = (unsigned char*)(W + 17 * MB);    // [M][64] uint8
    unsigned short* cat2 = (unsigned short*)(W + 24 * MB);   // [M][512]: 0-255 aggr2, 256-511 h1
    unsigned char*  xp2  = (unsigned char*)(W + 76 * MB);    // [M][256] uint8
    float* pooled = (float*)(W + 131 * MB);
    unsigned short* B0T  = (unsigned short*)(W + 133 * MB);  // [64][64]
    unsigned short* B1T  = (unsigned short*)(W + 134 * MB);  // [256][128]
    unsigned short* BP2T = (unsigned short*)(W + 135 * MB);  // [256][256]
    unsigned short* B2T  = (unsigned short*)(W + 136 * MB);  // [128][512]
    int*   boff   = (int*)(W + 137 * MB);                    // [512][196] = 401 KB
    int*   bcnt   = (int*)(W + 138 * MB);                    // [512][196] = 401 KB
    float* part   = (float*)(W + 140 * MB);                  // [GBLK][512] = 0.8 MB
    int*   tmp_e  = (int*)(W + 144 * MB);                    // [N_EDGES] = 3.2 MB

    // CSR build: fused hist+bucket-hist -> scans -> deterministic bucketed scatter
    hipMemsetAsync(counts, 0, N_NODES * sizeof(int), stream);
    k_bhist<<<NBK, 256, 0, stream>>>(dst, counts, bcnt);
    k_scan1<<<NB, 256, 0, stream>>>(counts, row_ptr, partial);
    k_scan3b<<<NB, 256, 0, stream>>>(row_ptr, partial);
    k_bscan<<<NB, 512, 0, stream>>>(bcnt, row_ptr, boff);
    k_split<<<(NWAVES + 1 + 255) / 256, 256, 0, stream>>>(row_ptr, split);
    k_bucket2<<<NBK, 256, 0, stream>>>(src, dst, boff, tmp_e);
    k_scatter2<<<NB, 256, 0, stream>>>(row_ptr, tmp_e, src_sorted);

    // fused casts (float4-vectorized; PREP_TOT divisible by 4)
    k_prep<<<(PREP_TOT / 4 + 255) / 256, 256, 0, stream>>>(
        x, w_proj1, w_l1, w_r1, w_proj2, w_l2, w_r2, cat1, B0T, B1T, BP2T, B2T);

    const int GB = GBLK;        // 391
    const int AGB = NWAVES / 4; // 2048

    // layer 1 (xp1 uint8: |msg1| < 12.75 hard bound)
    k_gemm<64, 64, 128, 64, 0, 3, 4, 2, 0><<<GB, 256, 0, stream>>>(
        cat1 + 64, B0T, b_proj1, xp1, nullptr, nullptr, nullptr, QINV1);
    k_aggr64<<<AGB, 256, 0, stream>>>(xp1, t1, row_ptr, src_sorted, split, cat1);
    k_gemm<128, 256, 128, 512, 256, 1, 3, 2, 0><<<GB, 256, 0, stream>>>(
        cat1, B1T, b_l1, cat2, nullptr, nullptr, nullptr, 0.f);

    // layer 2 (xp2 uint8; gemm4 fuses MemPool assignment AND partial S^T h2 -> part)
    k_gemm<256, 256, 512, 256, 0, 3, 3, 2, 0><<<GB, 256, 0, stream>>>(
        cat2 + 256, BP2T, b_proj2, xp2, nullptr, nullptr, nullptr, QINV2);
    k_aggr256<<<AGB, 256, 0, stream>>>(xp2, t2, row_ptr, src_sorted, split, cat2);
    k_gemm<512, 128, 512, 128, 0, 2, 3, 2, 1><<<GB, 256, 0, stream>>>(
        cat2, B2T, b_l2, part, k_mem, w_conv, nullptr, 0.f);

    // mempool reduce + head (pool_c fused into gemm4)
    k_pool_b<<<512, 256, 0, stream>>>(part, pooled);
    k_final<<<1, 128, 0, stream>>>(pooled, w_memlin, b_memlin, w_fx, b_fx, gamma, beta,
                                   (float*)d_out);
}

// Round 15
// 325.744 us; speedup vs baseline: 1.0726x; 1.0726x over previous
//
#include <hip/hip_runtime.h>
#include <hip/hip_bf16.h>

#define N_NODES 50000
#define N_EDGES 800000
#define NB 196   // ceil(N_NODES/256)
#define NBK 512  // bucket-pass blocks (2/CU)
#define EPB 1563 // edges per bucket-pass block (512*1563 >= 800000)
#define GBLK 391 // gemm blocks = ceil(N_NODES/128); also # of pool partials
#define NWAVES 8192  // streaming aggregation waves

typedef __attribute__((ext_vector_type(8))) short short8;
typedef __attribute__((ext_vector_type(4))) float f32x4;
typedef __attribute__((ext_vector_type(2))) float f32x2;

// int8 message quantization.
// Layer 2: h1 rows L2-normalized => |msg2| <= ||w_col||+|b| ~= 1.15 < 2 (hard).
// Layer 1: |msg1| <= max||x||*max||wp1_col||+|b| ~= 11.2*1.05+0.2 < 12.75 (hard).
#define QSCALE2 (2.f / 255.f)
#define QINV2   127.5f
#define QSCALE1 (12.75f / 255.f)   // = 0.05
#define QINV1   20.f

__device__ __forceinline__ float us2f(unsigned short u) {
    return __uint_as_float(((unsigned int)u) << 16);
}
__device__ __forceinline__ unsigned short f2bu(float f) {
    unsigned int u = __float_as_uint(f);
    unsigned int r = (u + 0x7fffu + ((u >> 16) & 1u)) >> 16;  // RNE
    return (unsigned short)r;
}
__device__ __forceinline__ float exp2_hw(float x) {
    float r;
    __asm__("v_exp_f32 %0, %1" : "=v"(r) : "v"(x));
    return r;
}
// async global->LDS, 16B per lane; LDS dest = wave-uniform base + lane*16
__device__ __forceinline__ void async16(const void* g, void* l) {
    __builtin_amdgcn_global_load_lds(
        (const __attribute__((address_space(1))) unsigned int*)g,
        (__attribute__((address_space(3))) unsigned int*)l, 16, 0, 0);
}
#define LOG2E 1.44269504088896f

// ---------------- CSR build ----------------
// k_hist fused into k_bhist: one pass over dst does both the per-node global
// atomicAdd (commutative -> deterministic) and the 196-bucket LDS histogram.
__global__ __launch_bounds__(256) void k_bhist(const int* __restrict__ dst,
                                               int* __restrict__ counts,
                                               int* __restrict__ bcnt) {
    __shared__ int h[196];
    int t = threadIdx.x, b = blockIdx.x;
    if (t < 196) h[t] = 0;
    __syncthreads();
    int e0 = b * EPB, e1 = e0 + EPB < N_EDGES ? e0 + EPB : N_EDGES;
    for (int e = e0 + t; e < e1; e += 256) {
        int d = dst[e];
        atomicAdd(&h[d >> 8], 1);   // LDS bucket histogram
        atomicAdd(&counts[d], 1);   // global per-node count (avg 16/counter)
    }
    __syncthreads();
    if (t < 196) bcnt[b * 196 + t] = h[t];
}

__global__ __launch_bounds__(256) void k_scan1(const int* __restrict__ counts,
                                               int* __restrict__ row_ptr,
                                               int* __restrict__ partial) {
    __shared__ int sd[256];
    int t = threadIdx.x, i = blockIdx.x * 256 + t;
    int v = (i < N_NODES) ? counts[i] : 0;
    sd[t] = v;
    __syncthreads();
    for (int off = 1; off < 256; off <<= 1) {
        int o = (t >= off) ? sd[t - off] : 0;
        __syncthreads();
        sd[t] += o;
        __syncthreads();
    }
    if (i < N_NODES) row_ptr[i] = sd[t] - v;
    if (t == 255) partial[blockIdx.x] = sd[255];
}

// scan3b: each block computes its own base (sum of partial[0..b-1]) then globalizes.
__global__ __launch_bounds__(256) void k_scan3b(int* __restrict__ row_ptr,
                                                const int* __restrict__ partial) {
    __shared__ int sd[256];
    int t = threadIdx.x;
    sd[t] = (t < blockIdx.x) ? partial[t] : 0;  // blockIdx < NB=196 < 256
    __syncthreads();
    for (int off = 128; off > 0; off >>= 1) {
        if (t < off) sd[t] += sd[t + off];
        __syncthreads();
    }
    int base = sd[0];
    int i = blockIdx.x * 256 + t;
    if (i < N_NODES) row_ptr[i] += base;
    if (blockIdx.x == 0 && t == 0) row_ptr[N_NODES] = N_EDGES;
}

// block q (196 blocks, 512 threads): exclusive scan of bcnt[b][q] over b.
__global__ __launch_bounds__(512) void k_bscan(const int* __restrict__ bcnt,
                                               const int* __restrict__ row_ptr,
                                               int* __restrict__ boff) {
    __shared__ int sd[512];
    int q = blockIdx.x, t = threadIdx.x;
    int v = bcnt[t * 196 + q];  // t < 512 = NBK
    sd[t] = v;
    __syncthreads();
    for (int off = 1; off < 512; off <<= 1) {
        int o = (t >= off) ? sd[t - off] : 0;
        __syncthreads();
        sd[t] += o;
        __syncthreads();
    }
    boff[t * 196 + q] = row_ptr[q * 256] + sd[t] - v;
}

__global__ __launch_bounds__(256) void k_bucket2(const int* __restrict__ src,
                                                 const int* __restrict__ dst,
                                                 const int* __restrict__ boff,
                                                 int* __restrict__ tmp) {
    __shared__ int lcur[196];
    int t = threadIdx.x, b = blockIdx.x;
    if (t < 196) lcur[t] = boff[b * 196 + t];
    __syncthreads();
    int e0 = b * EPB, e1 = e0 + EPB < N_EDGES ? e0 + EPB : N_EDGES;
    for (int e = e0 + t; e < e1; e += 256) {
        int d = dst[e];
        int pos = atomicAdd(&lcur[d >> 8], 1);  // LDS atomic: intra-block only
        tmp[pos] = src[e] | ((d & 255) << 16);  // src<50000<2^16
    }
}

__global__ __launch_bounds__(256) void k_scatter2(const int* __restrict__ row_ptr,
                                                  const int* __restrict__ tmp,
                                                  int* __restrict__ src_sorted) {
    __shared__ int lcur[256];
    int b = blockIdx.x, t = threadIdx.x;
    int n0 = b * 256;
    int nhi = n0 + 256 < N_NODES ? n0 + 256 : N_NODES;
    if (n0 + t < nhi) lcur[t] = row_ptr[n0 + t];
    __syncthreads();
    int ebeg = row_ptr[n0], eend = row_ptr[nhi];
    for (int i = ebeg + t; i < eend; i += 256) {
        int w = tmp[i];
        int pos = atomicAdd(&lcur[(w >> 16) & 255], 1);  // LDS atomic
        src_sorted[pos] = w & 0xFFFF;
    }
}

// ---------------- equal-edge wave partition ----------------
__global__ __launch_bounds__(256) void k_split(const int* __restrict__ row_ptr,
                                               int* __restrict__ split) {
    int w = blockIdx.x * 256 + threadIdx.x;
    if (w > NWAVES) return;
    if (w == NWAVES) { split[w] = N_NODES; return; }
    int target = (int)((long long)w * N_EDGES / NWAVES);
    int lo = 0, hi = N_NODES;
    while (lo < hi) {
        int mid = (lo + hi) >> 1;
        if (row_ptr[mid] < target) lo = mid + 1; else hi = mid;
    }
    split[w] = lo;
}

// ---------------- fused cast/transpose prep (float4-vectorized) ----------------
#define XCAST_N (N_NODES * 64)
#define PREP_TOT (XCAST_N + 167936)
__global__ __launch_bounds__(256) void k_prep(const float* __restrict__ x,
                                              const float* __restrict__ wp1,
                                              const float* __restrict__ wl1,
                                              const float* __restrict__ wr1,
                                              const float* __restrict__ wp2,
                                              const float* __restrict__ wl2,
                                              const float* __restrict__ wr2,
                                              unsigned short* __restrict__ cat1,
                                              unsigned short* __restrict__ B0T,
                                              unsigned short* __restrict__ B1T,
                                              unsigned short* __restrict__ BP2T,
                                              unsigned short* __restrict__ B2T) {
    int idx = (blockIdx.x * 256 + threadIdx.x) * 4;
    if (idx < XCAST_N) {
        int i = idx >> 6, j = idx & 63;
        float4 v = *(const float4*)&x[idx];
        ushort4 o = { f2bu(v.x), f2bu(v.y), f2bu(v.z), f2bu(v.w) };
        *(ushort4*)&cat1[i * 128 + 64 + j] = o;
        return;
    }
    int w = idx - XCAST_N;
    if (w < 4096)  { float4 v = *(const float4*)&wp1[w]; int k = w >> 6, n = w & 63;
                     B0T[n*64+k]=f2bu(v.x); B0T[(n+1)*64+k]=f2bu(v.y);
                     B0T[(n+2)*64+k]=f2bu(v.z); B0T[(n+3)*64+k]=f2bu(v.w); return; }
    w -= 4096;
    if (w < 16384) { float4 v = *(const float4*)&wl1[w]; int k = w >> 8, n = w & 255;
                     B1T[n*128+k]=f2bu(v.x); B1T[(n+1)*128+k]=f2bu(v.y);
                     B1T[(n+2)*128+k]=f2bu(v.z); B1T[(n+3)*128+k]=f2bu(v.w); return; }
    w -= 16384;
    if (w < 16384) { float4 v = *(const float4*)&wr1[w]; int k = w >> 8, n = w & 255;
                     B1T[n*128+64+k]=f2bu(v.x); B1T[(n+1)*128+64+k]=f2bu(v.y);
                     B1T[(n+2)*128+64+k]=f2bu(v.z); B1T[(n+3)*128+64+k]=f2bu(v.w); return; }
    w -= 16384;
    if (w < 65536) { float4 v = *(const float4*)&wp2[w]; int k = w >> 8, n = w & 255;
                     BP2T[n*256+k]=f2bu(v.x); BP2T[(n+1)*256+k]=f2bu(v.y);
                     BP2T[(n+2)*256+k]=f2bu(v.z); BP2T[(n+3)*256+k]=f2bu(v.w); return; }
    w -= 65536;
    if (w < 32768) { float4 v = *(const float4*)&wl2[w]; int k = w >> 7, n = w & 127;
                     B2T[n*512+k]=f2bu(v.x); B2T[(n+1)*512+k]=f2bu(v.y);
                     B2T[(n+2)*512+k]=f2bu(v.z); B2T[(n+3)*512+k]=f2bu(v.w); return; }
    w -= 32768;
    if (w < 32768) { float4 v = *(const float4*)&wr2[w]; int k = w >> 7, n = w & 127;
                     B2T[n*512+256+k]=f2bu(v.x); B2T[(n+1)*512+256+k]=f2bu(v.y);
                     B2T[(n+2)*512+256+k]=f2bu(v.z); B2T[(n+3)*512+256+k]=f2bu(v.w); return; }
}

// ---------------- MFMA bf16 GEMM, 128-row tile, async staging, fused epilogue ----
// PIPE=1: 2-phase pipelined staging (double-buffered LDS).
// EP2 fully fuses the MemPool (S in LDS, partial S^T h2 per block, only 512
// floats written). Round-14 lesson: the 64-iter pool loop must be unroll-capped
// or the compiler pipelines 128 LDS loads into registers (VGPR 76->160,
// occupancy 8%). #pragma unroll 4 keeps <=8 live loads.
template<int K, int C, int LDA, int LDOUT, int OUT_OFF, int EP, int WPB, int MH, int PIPE>
__global__ __launch_bounds__(256, WPB) void k_gemm(const unsigned short* __restrict__ A,
                                                   const unsigned short* __restrict__ BT,
                                                   const float* __restrict__ bias,
                                                   void* __restrict__ outv,
                                                   const float* __restrict__ kmem,
                                                   const float* __restrict__ wconv,
                                                   float* __restrict__ Sm,
                                                   float qinv) {
    constexpr int NT = C / 16;
    constexpr int SAE = 64 * MH * 64;  // elems, stride 64 (linear for gload_lds)
    constexpr int SBE = C * 64;
    constexpr int BUFE = SAE + SBE;
    constexpr int STAGE_B = BUFE * 2 * (PIPE ? 2 : 1);
    constexpr int RPLD = (EP == 2) ? (C + 4) : ((EP == 3) ? (C + 16) : (C + 8));
    constexpr int RP_B = 64 * RPLD * (EP == 2 ? 4 : (EP == 3 ? 1 : 2));
    constexpr int SMEM_B = STAGE_B > RP_B ? STAGE_B : RP_B;
    constexpr int POOL_B = (EP == 2) ? (2048 * 4 + 64 + 16 + 1024) : 16;
    __shared__ __align__(16) char smem[SMEM_B + POOL_B];
    unsigned short* sA = (unsigned short*)smem;
    float* kls  = (float*)(smem + SMEM_B);  // EP2 only: 2048 floats
    float* kk2s = kls + 2048;               // 16
    float* wcs  = kk2s + 16;                // 4
    float* sS   = wcs + 4;                  // EP2 only: 64 rows x 4 clusters

    int t = threadIdx.x;
    int wid = t >> 6, lane = t & 63;
    int lrow = lane & 15, quad = lane >> 4;
    int m0 = blockIdx.x * (64 * MH);

    if (EP == 2) {  // stage mempool keys once per block
        for (int i = t; i < 2048; i += 256) kls[i] = kmem[i];
        if (t < 4) wcs[t] = wconv[t];
        __syncthreads();
        if (t < 16) {
            float s = 0.f;
            for (int f = 0; f < 128; ++f) { float v = kls[t * 128 + f]; s += v * v; }
            kk2s[t] = s;
        }
    }

    f32x4 acc[MH][NT];
#pragma unroll
    for (int h = 0; h < MH; ++h)
#pragma unroll
        for (int nt = 0; nt < NT; ++nt)
#pragma unroll
            for (int r = 0; r < 4; ++r) acc[h][nt][r] = 0.f;

    auto stage = [&](int step, int buf) {
        unsigned short* sAb = sA + buf * BUFE;
        unsigned short* sBb = sAb + SAE;
        int k0 = step * 64;
        for (int i = t; i < 64 * MH * 8; i += 256) {
            int r = i >> 3, seg = i & 7;
            size_t m = (size_t)(m0 + r);
            async16(&A[m * LDA + k0 + ((seg ^ (r & 7)) << 3)],
                    (char*)sAb + (size_t)(i - lane) * 16);
        }
        for (int i = t; i < C * 8; i += 256) {
            int n = i >> 3, seg = i & 7;
            async16(&BT[(size_t)n * K + k0 + ((seg ^ (n & 7)) << 3)],
                    (char*)sBb + (size_t)(i - lane) * 16);
        }
    };
    auto compute = [&](int buf) {
        unsigned short* sAb = sA + buf * BUFE;
        unsigned short* sBb = sAb + SAE;
#pragma unroll
        for (int kk = 0; kk < 2; ++kk) {
            int sw = lrow & 7;
            short8 av[MH];
#pragma unroll
            for (int h = 0; h < MH; ++h)
                av[h] = *(const short8*)&sAb[(h * 64 + wid * 16 + lrow) * 64 +
                                             (((kk * 4 + quad) ^ sw) << 3)];
#pragma unroll
            for (int nt = 0; nt < NT; ++nt) {
                short8 bfg = *(const short8*)&sBb[(nt * 16 + lrow) * 64 +
                                                  (((kk * 4 + quad) ^ sw) << 3)];
#pragma unroll
                for (int h = 0; h < MH; ++h)
                    acc[h][nt] = __builtin_amdgcn_mfma_f32_16x16x32_bf16(av[h], bfg, acc[h][nt], 0, 0, 0);
            }
        }
    };

    constexpr int NSTEP = K / 64;
    if (PIPE) {
        stage(0, 0);
        __syncthreads();  // drains stage(0)
        for (int step = 0; step < NSTEP; ++step) {
            int cur = step & 1;
            if (step + 1 < NSTEP) stage(step + 1, cur ^ 1);  // in flight during compute
            compute(cur);
            __syncthreads();  // drains stage(step+1) after it overlapped compute
        }
    } else {
        for (int step = 0; step < NSTEP; ++step) {
            __syncthreads();
            stage(step, 0);
            __syncthreads();
            compute(0);
        }
    }

#pragma unroll
    for (int h = 0; h < MH; ++h) {
#pragma unroll
        for (int nt = 0; nt < NT; ++nt) {
            float bv = bias[nt * 16 + lrow];
#pragma unroll
            for (int r = 0; r < 4; ++r) acc[h][nt][r] += bv;
        }
        if (EP == 1 || EP == 2) {
#pragma unroll
            for (int r = 0; r < 4; ++r) {
                float ss = 0.f;
#pragma unroll
                for (int nt = 0; nt < NT; ++nt) ss += acc[h][nt][r] * acc[h][nt][r];
                ss += __shfl_xor(ss, 1);
                ss += __shfl_xor(ss, 2);
                ss += __shfl_xor(ss, 4);
                ss += __shfl_xor(ss, 8);
                float rinv = 1.f / fmaxf(sqrtf(ss), 1e-12f);
#pragma unroll
                for (int nt = 0; nt < NT; ++nt)
                    acc[h][nt][r] = fmaxf(acc[h][nt][r] * rinv, 0.f);
            }
        } else {
#pragma unroll
            for (int nt = 0; nt < NT; ++nt)
#pragma unroll
                for (int r = 0; r < 4; ++r) acc[h][nt][r] = fmaxf(acc[h][nt][r], 0.f);
        }
    }

    float pacc0 = 0.f, pacc1 = 0.f;  // EP2: this thread's 2 pool-partial outputs

    __syncthreads();
#pragma unroll
    for (int h = 0; h < MH; ++h) {
        if (EP == 2) {
            float* rp = (float*)smem;
#pragma unroll
            for (int nt = 0; nt < NT; ++nt)
#pragma unroll
                for (int r = 0; r < 4; ++r)
                    rp[(wid * 16 + quad * 4 + r) * RPLD + nt * 16 + lrow] = acc[h][nt][r];
            __syncthreads();
            // mempool assignment (4 threads/row, shuffle-combine) -> S into sS LDS
            {
                int row = t >> 2, p = t & 3;
                int cbase = p * 32;
                float dots[16];
#pragma unroll
                for (int k = 0; k < 16; ++k) dots[k] = 0.f;
                float x2 = 0.f;
#pragma unroll
                for (int j = 0; j < 8; ++j) {
                    int c4 = (j + p * 2) & 7;
                    float4 xv = *(const float4*)&rp[row * RPLD + cbase + c4 * 4];
                    x2 += xv.x * xv.x + xv.y * xv.y + xv.z * xv.z + xv.w * xv.w;
#pragma unroll
                    for (int k = 0; k < 16; ++k) {
                        float4 kv = *(const float4*)&kls[k * 128 + cbase + c4 * 4];
                        dots[k] += xv.x * kv.x + xv.y * kv.y + xv.z * kv.z + xv.w * kv.w;
                    }
                }
#pragma unroll
                for (int k = 0; k < 16; ++k) {
                    dots[k] += __shfl_xor(dots[k], 1);
                    dots[k] += __shfl_xor(dots[k], 2);
                }
                x2 += __shfl_xor(x2, 1);
                x2 += __shfl_xor(x2, 2);
                if (p == 0) {
                    int m = m0 + h * 64 + row;
                    float4 sv = make_float4(0.f, 0.f, 0.f, 0.f);
                    if (m < N_NODES) {
                        float dist[16];
#pragma unroll
                        for (int k = 0; k < 16; ++k) {
                            float d2 = fmaxf(kk2s[k] + x2 - 2.f * dots[k], 0.f);
                            dist[k] = 1.f / (1.f + d2);
                        }
                        float s0 = 0.f, s1 = 0.f, s2 = 0.f, s3 = 0.f;
#pragma unroll
                        for (int hh = 0; hh < 4; ++hh) {
                            float den = dist[hh * 4] + dist[hh * 4 + 1] +
                                        dist[hh * 4 + 2] + dist[hh * 4 + 3];
                            float inv = wcs[hh] / den;
                            s0 += dist[hh * 4 + 0] * inv;
                            s1 += dist[hh * 4 + 1] * inv;
                            s2 += dist[hh * 4 + 2] * inv;
                            s3 += dist[hh * 4 + 3] * inv;
                        }
                        float mx = fmaxf(fmaxf(s0, s1), fmaxf(s2, s3));
                        float e0 = __expf(s0 - mx), e1 = __expf(s1 - mx);
                        float e2 = __expf(s2 - mx), e3 = __expf(s3 - mx);
                        float inv = 1.f / (e0 + e1 + e2 + e3);
                        sv = make_float4(e0 * inv, e1 * inv, e2 * inv, e3 * inv);
                    }
                    *(float4*)&sS[row * 4] = sv;
                }
            }
            __syncthreads();
            // per-block partial of S^T h2: output o=t -> (k=t>>7, c=t&127),
            // o=t+256 -> (k=2+(t>>7), c). rp reads stride-1 (conflict-free),
            // sS reads broadcast. OOB rows contribute 0 via sS.
            // unroll-capped: full unroll pipelined 128 LDS loads -> VGPR 160.
            {
                int c = t & 127, kq = t >> 7;
#pragma unroll 4
                for (int r = 0; r < 64; ++r) {
                    float xv = rp[r * RPLD + c];
                    pacc0 = fmaf(sS[r * 4 + kq], xv, pacc0);
                    pacc1 = fmaf(sS[r * 4 + 2 + kq], xv, pacc1);
                }
            }
            __syncthreads();
        } else if (EP == 3) {
            unsigned char* rp = (unsigned char*)smem;
#pragma unroll
            for (int nt = 0; nt < NT; ++nt)
#pragma unroll
                for (int r = 0; r < 4; ++r) {
                    float q = fminf(__builtin_rintf(acc[h][nt][r] * qinv), 255.f);
                    rp[(wid * 16 + quad * 4 + r) * RPLD + nt * 16 + lrow] = (unsigned char)(int)q;
                }
            __syncthreads();
            unsigned char* outp = (unsigned char*)outv;
            for (int i = t; i < 64 * C / 16; i += 256) {
                int f = i * 16, r = f / C, c = f % C;
                int m = m0 + h * 64 + r;
                if (m < N_NODES)
                    *(uint4*)&outp[(size_t)m * LDOUT + OUT_OFF + c] = *(const uint4*)&rp[r * RPLD + c];
            }
            __syncthreads();
        } else {
            unsigned short* rp = (unsigned short*)smem;
#pragma unroll
            for (int nt = 0; nt < NT; ++nt)
#pragma unroll
                for (int r = 0; r < 4; ++r)
                    rp[(wid * 16 + quad * 4 + r) * RPLD + nt * 16 + lrow] = f2bu(acc[h][nt][r]);
            __syncthreads();
            unsigned short* outp = (unsigned short*)outv;
            for (int i = t; i < 64 * C / 8; i += 256) {
                int f = i * 8, r = f / C, c = f % C;
                int m = m0 + h * 64 + r;
                if (m < N_NODES)
                    *(uint4*)&outp[(size_t)m * LDOUT + OUT_OFF + c] = *(const uint4*)&rp[r * RPLD + c];
            }
            __syncthreads();
        }
    }
    if (EP == 2) {
        float* partp = (float*)outv;
        partp[(size_t)blockIdx.x * 512 + t] = pacc0;
        partp[(size_t)blockIdx.x * 512 + 256 + t] = pacc1;
    }
    (void)Sm;
}

// ---------------- streaming segmented softmax aggregation (layer 2) ----------------
// Frozen at the round-10 equilibrium form (6 structural variants all >=51us).
__global__ __launch_bounds__(256, 4) void k_aggr256(const unsigned char* __restrict__ xp,
                                                    const float* __restrict__ tvec,
                                                    const int* __restrict__ row_ptr,
                                                    const int* __restrict__ srcs,
                                                    const int* __restrict__ split,
                                                    unsigned short* __restrict__ outp) {
    int t = threadIdx.x & 63;  // 4 channels per thread
    int w = blockIdx.x * 4 + (threadIdx.x >> 6);
    float4 tv4 = *(const float4*)&tvec[t * 4];
    f32x2 tv01 = {tv4.x * (LOG2E * QSCALE2), tv4.y * (LOG2E * QSCALE2)};
    f32x2 tv23 = {tv4.z * (LOG2E * QSCALE2), tv4.w * (LOG2E * QSCALE2)};
    int n    = __builtin_amdgcn_readfirstlane(split[w]);
    int nend = __builtin_amdgcn_readfirstlane(split[w + 1]);
    if (n >= nend) return;
    int e    = __builtin_amdgcn_readfirstlane(row_ptr[n]);
    int eend = __builtin_amdgcn_readfirstlane(row_ptr[nend]);
    int rp_next = __builtin_amdgcn_readfirstlane(row_ptr[n + 1]);
    f32x2 se01 = {0.f, 0.f}, se23 = {0.f, 0.f};
    f32x2 sem01 = {0.f, 0.f}, sem23 = {0.f, 0.f};

#define FINALIZE()                                                             \
    {                                                                          \
        ushort4 o;                                                             \
        o.x = f2bu(QSCALE2 * sem01.x / fmaxf(se01.x, 1e-16f));                 \
        o.y = f2bu(QSCALE2 * sem01.y / fmaxf(se01.y, 1e-16f));                 \
        o.z = f2bu(QSCALE2 * sem23.x / fmaxf(se23.x, 1e-16f));                 \
        o.w = f2bu(QSCALE2 * sem23.y / fmaxf(se23.y, 1e-16f));                 \
        *(ushort4*)&outp[(size_t)n * 512 + t * 4] = o;                         \
        se01 = (f32x2){0.f, 0.f}; se23 = (f32x2){0.f, 0.f};                    \
        sem01 = (f32x2){0.f, 0.f}; sem23 = (f32x2){0.f, 0.f};                  \
        ++n;                                                                   \
        rp_next = (n < nend) ? __builtin_amdgcn_readfirstlane(row_ptr[n + 1])  \
                             : 0x7FFFFFFF;                                     \
    }
#define EDGE_BODY(VV)                                                          \
    {                                                                          \
        f32x2 m01 = {(float)((VV) & 0xFFu), (float)(((VV) >> 8) & 0xFFu)};     \
        f32x2 m23 = {(float)(((VV) >> 16) & 0xFFu), (float)((VV) >> 24)};      \
        f32x2 l01 = m01 * tv01, l23 = m23 * tv23;                              \
        f32x2 w01, w23;                                                        \
        w01.x = exp2_hw(l01.x); w01.y = exp2_hw(l01.y);                        \
        w23.x = exp2_hw(l23.x); w23.y = exp2_hw(l23.y);                        \
        se01 += w01; se23 += w23;                                              \
        sem01 = __builtin_elementwise_fma(w01, m01, sem01);                    \
        sem23 = __builtin_elementwise_fma(w23, m23, sem23);                    \
    }

    while (rp_next <= e) FINALIZE();  // leading empty nodes (write zeros)

    while (e < eend) {
        unsigned int v[16];
        int rem = eend - e;
        int cnt = rem > 16 ? 16 : rem;
        if (cnt == 16) {
#pragma unroll
            for (int j = 0; j < 16; ++j) {
                const unsigned char* p = xp + (size_t)srcs[e + j] * 256;  // uniform base
                v[j] = *(const unsigned int*)&p[t * 4];
            }
        } else {  // single short batch per wave
#pragma unroll
            for (int j = 0; j < 16; ++j) {
                int ee = e + j;
                ee = ee < eend ? ee : eend - 1;
                const unsigned char* p = xp + (size_t)srcs[ee] * 256;
                v[j] = *(const unsigned int*)&p[t * 4];
            }
        }
#pragma unroll
        for (int j = 0; j < 16; ++j) {
            if (j < cnt) {
                EDGE_BODY(v[j])
                while (e + j + 1 == rp_next) FINALIZE();  // also drains empty nodes
            }
        }
        e += cnt;
    }
#undef EDGE_BODY
#undef FINALIZE
}

// C=64 variant (layer 1): same streaming structure, 1 byte/lane/edge.
__global__ __launch_bounds__(256, 4) void k_aggr64(const unsigned char* __restrict__ xp,
                                                   const float* __restrict__ tvec,
                                                   const int* __restrict__ row_ptr,
                                                   const int* __restrict__ srcs,
                                                   const int* __restrict__ split,
                                                   unsigned short* __restrict__ outp) {
    int c = threadIdx.x & 63;  // channel 0..63
    int w = blockIdx.x * 4 + (threadIdx.x >> 6);
    float tv = tvec[c] * (LOG2E * QSCALE1);
    int n    = __builtin_amdgcn_readfirstlane(split[w]);
    int nend = __builtin_amdgcn_readfirstlane(split[w + 1]);
    if (n >= nend) return;
    int e    = __builtin_amdgcn_readfirstlane(row_ptr[n]);
    int eend = __builtin_amdgcn_readfirstlane(row_ptr[nend]);
    int rp_next = __builtin_amdgcn_readfirstlane(row_ptr[n + 1]);
    float se = 0.f, sem = 0.f;

#define FIN1()                                                                 \
    {                                                                          \
        outp[(size_t)n * 128 + c] = f2bu(QSCALE1 * sem / fmaxf(se, 1e-16f));   \
        se = 0.f; sem = 0.f;                                                   \
        ++n;                                                                   \
        rp_next = (n < nend) ? __builtin_amdgcn_readfirstlane(row_ptr[n + 1])  \
                             : 0x7FFFFFFF;                                     \
    }

    while (rp_next <= e) FIN1();

    while (e < eend) {
        unsigned char v[16];
        int rem = eend - e;
        int cnt = rem > 16 ? 16 : rem;
        if (cnt == 16) {
#pragma unroll
            for (int j = 0; j < 16; ++j)
                v[j] = xp[(size_t)srcs[e + j] * 64 + c];
        } else {
#pragma unroll
            for (int j = 0; j < 16; ++j) {
                int ee = e + j;
                ee = ee < eend ? ee : eend - 1;
                v[j] = xp[(size_t)srcs[ee] * 64 + c];
            }
        }
#pragma unroll
        for (int j = 0; j < 16; ++j) {
            if (j < cnt) {
                float msg = (float)v[j];
                float wv = exp2_hw(msg * tv);
                se += wv;
                sem = fmaf(wv, msg, sem);
                while (e + j + 1 == rp_next) FIN1();
            }
        }
        e += cnt;
    }
#undef FIN1
}

// ---------------- MemPool reduce: sum GBLK block-partials ----------------
__global__ __launch_bounds__(256) void k_pool_b(const float* __restrict__ part,
                                                float* __restrict__ pooled) {
    int j = blockIdx.x;  // 0..511
    float s = 0.f;
    for (int b = threadIdx.x; b < GBLK; b += 256) s += part[(size_t)b * 512 + j];
#pragma unroll
    for (int off = 32; off > 0; off >>= 1) s += __shfl_xor(s, off);
    __shared__ float red[4];
    int lane = threadIdx.x & 63, wid = threadIdx.x >> 6;
    if (lane == 0) red[wid] = s;
    __syncthreads();
    if (threadIdx.x == 0) pooled[j] = red[0] + red[1] + red[2] + red[3];
}

__global__ __launch_bounds__(128) void k_final(const float* __restrict__ pooled,
                                               const float* __restrict__ wmem,
                                               const float* __restrict__ bmem,
                                               const float* __restrict__ wfx,
                                               const float* __restrict__ bfx,
                                               const float* __restrict__ gamma,
                                               const float* __restrict__ beta,
                                               float* __restrict__ out) {
    __shared__ float gx[128], g[128];
    int t = threadIdx.x;
    gx[t] = 0.25f * (pooled[t] + pooled[128 + t] + pooled[256 + t] + pooled[384 + t]);
    __syncthreads();
    float acc = bmem[t];
    for (int f = 0; f < 128; ++f) acc = fmaf(gx[f], wmem[f * 128 + t], acc);
    g[t] = acc;
    __syncthreads();
    if (t < 64) {
        float y = bfx[t];
        for (int f = 0; f < 128; ++f) y = fmaf(g[f], wfx[f * 64 + t], y);
        float s = y, s2 = y * y;
#pragma unroll
        for (int off = 32; off > 0; off >>= 1) {
            s += __shfl_xor(s, off);
            s2 += __shfl_xor(s2, off);
        }
        float mu = s * (1.f / 64.f);
        float var = s2 * (1.f / 64.f) - mu * mu;
        float v = (y - mu) / sqrtf(var + 1e-5f) * gamma[t] + beta[t];
        out[t] = fmaxf(v, 0.f);
    }
}

extern "C" void kernel_launch(void* const* d_in, const int* in_sizes, int n_in,
                              void* d_out, int out_size, void* d_ws, size_t ws_size,
                              hipStream_t stream) {
    const float* x        = (const float*)d_in[0];
    const int*   ei       = (const int*)  d_in[1];
    const float* w_proj1  = (const float*)d_in[2];
    const float* b_proj1  = (const float*)d_in[3];
    const float* t1       = (const float*)d_in[4];
    const float* w_l1     = (const float*)d_in[5];
    const float* b_l1     = (const float*)d_in[6];
    const float* w_r1     = (const float*)d_in[7];
    const float* w_proj2  = (const float*)d_in[8];
    const float* b_proj2  = (const float*)d_in[9];
    const float* t2       = (const float*)d_in[10];
    const float* w_l2     = (const float*)d_in[11];
    const float* b_l2     = (const float*)d_in[12];
    const float* w_r2     = (const float*)d_in[13];
    const float* k_mem    = (const float*)d_in[14];
    const float* w_conv   = (const float*)d_in[15];
    const float* w_memlin = (const float*)d_in[16];
    const float* b_memlin = (const float*)d_in[17];
    const float* w_fx     = (const float*)d_in[18];
    const float* b_fx     = (const float*)d_in[19];
    const float* gamma    = (const float*)d_in[20];
    const float* beta     = (const float*)d_in[21];
    const int* src = ei;
    const int* dst = ei + N_EDGES;
    (void)in_sizes; (void)n_in; (void)out_size; (void)ws_size;

    char* W = (char*)d_ws;
    const size_t MB = 1024 * 1024;
    int*   row_ptr    = (int*)(W + 0);
    int*   counts     = (int*)(W + 256 * 1024);
    int*   partial    = (int*)(W + 512 * 1024);
    int*   split      = (int*)(W + 520 * 1024);              // [NWAVES+1] = 32.8 KB
    int*   src_sorted = (int*)(W + 768 * 1024);
    unsigned short* cat1 = (unsigned short*)(W + 4 * MB);    // [M][128]: 0-63 aggr1, 64-127 x
    unsigned char*  xp1  = (unsigned char*)(W + 17 * MB);    // [M][64] uint8
    unsigned short* cat2 = (unsigned short*)(W + 24 * MB);   // [M][512]: 0-255 aggr2, 256-511 h1
    unsigned char*  xp2  = (unsigned char*)(W + 76 * MB);    // [M][256] uint8
    float* pooled = (float*)(W + 131 * MB);
    unsigned short* B0T  = (unsigned short*)(W + 133 * MB);  // [64][64]
    unsigned short* B1T  = (unsigned short*)(W + 134 * MB);  // [256][128]
    unsigned short* BP2T = (unsigned short*)(W + 135 * MB);  // [256][256]
    unsigned short* B2T  = (unsigned short*)(W + 136 * MB);  // [128][512]
    int*   boff   = (int*)(W + 137 * MB);                    // [512][196] = 401 KB
    int*   bcnt   = (int*)(W + 138 * MB);                    // [512][196] = 401 KB
    float* part   = (float*)(W + 140 * MB);                  // [GBLK][512] = 0.8 MB
    int*   tmp_e  = (int*)(W + 144 * MB);                    // [N_EDGES] = 3.2 MB

    // CSR build: fused hist+bucket-hist -> scans -> deterministic bucketed scatter
    hipMemsetAsync(counts, 0, N_NODES * sizeof(int), stream);
    k_bhist<<<NBK, 256, 0, stream>>>(dst, counts, bcnt);
    k_scan1<<<NB, 256, 0, stream>>>(counts, row_ptr, partial);
    k_scan3b<<<NB, 256, 0, stream>>>(row_ptr, partial);
    k_bscan<<<NB, 512, 0, stream>>>(bcnt, row_ptr, boff);
    k_split<<<(NWAVES + 1 + 255) / 256, 256, 0, stream>>>(row_ptr, split);
    k_bucket2<<<NBK, 256, 0, stream>>>(src, dst, boff, tmp_e);
    k_scatter2<<<NB, 256, 0, stream>>>(row_ptr, tmp_e, src_sorted);

    // fused casts (float4-vectorized; PREP_TOT divisible by 4)
    k_prep<<<(PREP_TOT / 4 + 255) / 256, 256, 0, stream>>>(
        x, w_proj1, w_l1, w_r1, w_proj2, w_l2, w_r2, cat1, B0T, B1T, BP2T, B2T);

    const int GB = GBLK;        // 391
    const int AGB = NWAVES / 4; // 2048

    // layer 1 (xp1 uint8: |msg1| < 12.75 hard bound)
    k_gemm<64, 64, 128, 64, 0, 3, 4, 2, 0><<<GB, 256, 0, stream>>>(
        cat1 + 64, B0T, b_proj1, xp1, nullptr, nullptr, nullptr, QINV1);
    k_aggr64<<<AGB, 256, 0, stream>>>(xp1, t1, row_ptr, src_sorted, split, cat1);
    k_gemm<128, 256, 128, 512, 256, 1, 3, 2, 0><<<GB, 256, 0, stream>>>(
        cat1, B1T, b_l1, cat2, nullptr, nullptr, nullptr, 0.f);

    // layer 2 (xp2 uint8; gemm4 fuses MemPool assignment AND partial S^T h2 -> part)
    k_gemm<256, 256, 512, 256, 0, 3, 3, 2, 0><<<GB, 256, 0, stream>>>(
        cat2 + 256, BP2T, b_proj2, xp2, nullptr, nullptr, nullptr, QINV2);
    k_aggr256<<<AGB, 256, 0, stream>>>(xp2, t2, row_ptr, src_sorted, split, cat2);
    k_gemm<512, 128, 512, 128, 0, 2, 3, 2, 1><<<GB, 256, 0, stream>>>(
        cat2, B2T, b_l2, part, k_mem, w_conv, nullptr, 0.f);

    // mempool reduce + head (pool_c fused into gemm4)
    k_pool_b<<<512, 256, 0, stream>>>(part, pooled);
    k_final<<<1, 128, 0, stream>>>(pooled, w_memlin, b_memlin, w_fx, b_fx, gamma, beta,
                                   (float*)d_out);
}